// Round 1
// baseline (1319.534 us; speedup 1.0000x reference)
//
#include <hip/hip_runtime.h>

// Problem constants (MeshConv: B=8, M=40000, FIN=64, K=6, FOUT=64, NNZ=320000)
#define Mn    40000
#define Bn    8
#define FINn  64
#define Kn    6
#define FOUTn 64
#define NNZn  320000
#define Cn    512   // FIN*B columns per Chebyshev level

// ---------------- CSR build ----------------

__global__ __launch_bounds__(256) void k_hist(const int* __restrict__ rows,
                                              int* __restrict__ cnt) {
    int e = blockIdx.x * 256 + threadIdx.x;
    if (e < NNZn) atomicAdd(&cnt[rows[e]], 1);
}

__global__ __launch_bounds__(1024) void k_scan(const int* __restrict__ cnt,
                                               int* __restrict__ rowptr) {
    __shared__ int tmp[1024];
    __shared__ int carry_s;
    int tid = threadIdx.x;
    if (tid == 0) carry_s = 0;
    __syncthreads();
    for (int base = 0; base < Mn; base += 1024) {
        int i = base + tid;
        int v = (i < Mn) ? cnt[i] : 0;
        tmp[tid] = v;
        __syncthreads();
        for (int off = 1; off < 1024; off <<= 1) {
            int t = (tid >= off) ? tmp[tid - off] : 0;
            __syncthreads();
            tmp[tid] += t;
            __syncthreads();
        }
        if (i < Mn) rowptr[i] = carry_s + tmp[tid] - v;   // exclusive
        __syncthreads();
        if (tid == 0) carry_s += tmp[1023];
        __syncthreads();
    }
    if (tid == 0) rowptr[Mn] = carry_s;
}

__global__ __launch_bounds__(256) void k_scatter(const int* __restrict__ rows,
                                                 const int* __restrict__ cols,
                                                 const float* __restrict__ vals,
                                                 const int* __restrict__ rowptr,
                                                 int* __restrict__ fill,
                                                 int* __restrict__ csr_col,
                                                 float* __restrict__ csr_val) {
    int e = blockIdx.x * 256 + threadIdx.x;
    if (e < NNZn) {
        int r = rows[e];
        int p = rowptr[r] + atomicAdd(&fill[r], 1);
        csr_col[p] = cols[e];
        csr_val[p] = vals[e];
    }
}

// ---------------- x -> x0 transpose: x0[m, f*8+b] = x[b,m,f] ----------------

__global__ __launch_bounds__(512) void k_transpose(const float* __restrict__ x,
                                                   float* __restrict__ x0) {
    __shared__ float ld[64 * 9];  // 64 f x 8 b, pad 9 to break bank conflicts
    int m = blockIdx.x, t = threadIdx.x;       // t = b*64 + f (coalesced read)
    int b = t >> 6, f = t & 63;
    ld[f * 9 + b] = x[((size_t)b * Mn + m) * 64 + f];
    __syncthreads();
    int fb = t >> 3, bb = t & 7;               // c = t = fb*8+bb (coalesced write)
    x0[(size_t)m * Cn + t] = ld[fb * 9 + bb];
}

// ---------------- SpMM + Chebyshev recurrence ----------------
// acc = (L - I) xc ; xn = first ? acc : 2*acc - xp

__global__ __launch_bounds__(128) void k_spmm(const float4* __restrict__ xc,
                                              const float4* __restrict__ xp,
                                              float4* __restrict__ xn,
                                              const int* __restrict__ rowptr,
                                              const int* __restrict__ csr_col,
                                              const float* __restrict__ csr_val,
                                              int first) {
    int m = blockIdx.x, t = threadIdx.x;   // 128 threads x float4 = 512 floats
    float4 v = xc[(size_t)m * 128 + t];
    float4 acc = make_float4(-v.x, -v.y, -v.z, -v.w);
    int beg = rowptr[m], end = rowptr[m + 1];
    for (int e = beg; e < end; ++e) {
        float val = csr_val[e];
        float4 g = xc[(size_t)csr_col[e] * 128 + t];
        acc.x += val * g.x; acc.y += val * g.y;
        acc.z += val * g.z; acc.w += val * g.w;
    }
    if (!first) {
        float4 p = xp[(size_t)m * 128 + t];
        acc.x = 2.f * acc.x - p.x; acc.y = 2.f * acc.y - p.y;
        acc.z = 2.f * acc.z - p.z; acc.w = 2.f * acc.w - p.w;
    }
    xn[(size_t)m * 128 + t] = acc;
}

// ---------------- paired-level projection GEMM ----------------
// out[b, m, fo] (+)= sum_f xa[m, f*8+b]*W[f*6+ka, fo] + xb[m, f*8+b]*W[f*6+kb, fo]
// Block: 4 rows m, 256 threads; W slices + x rows staged in LDS.

__global__ __launch_bounds__(256) void k_gemm2(const float* __restrict__ xa,
                                               const float* __restrict__ xb,
                                               const float* __restrict__ W,
                                               float* __restrict__ out,
                                               int ka, int kb, int accum) {
    __shared__ __align__(16) float Wa[64 * 64];
    __shared__ __align__(16) float Wb[64 * 64];
    __shared__ __align__(16) float xsa[4 * Cn];
    __shared__ __align__(16) float xsb[4 * Cn];
    int t = threadIdx.x;
    size_t m0 = (size_t)blockIdx.x * 4;

    for (int i = t; i < 4096; i += 256) {
        int f = i >> 6, fo = i & 63;
        Wa[i] = W[(f * Kn + ka) * FOUTn + fo];
        Wb[i] = W[(f * Kn + kb) * FOUTn + fo];
    }
    for (int i = t; i < 4 * Cn; i += 256) {
        xsa[i] = xa[m0 * Cn + i];
        xsb[i] = xb[m0 * Cn + i];
    }
    __syncthreads();

    int fo  = (t & 15) * 4;
    int idx = t >> 4;            // 0..15
    int m   = idx & 3;
    int bq  = idx >> 2;          // b in {bq, bq+4}
    float4 acc0 = make_float4(0.f, 0.f, 0.f, 0.f);
    float4 acc1 = make_float4(0.f, 0.f, 0.f, 0.f);

    for (int f = 0; f < 64; ++f) {
        float4 wa = *(const float4*)&Wa[f * 64 + fo];
        float a0 = xsa[m * Cn + f * 8 + bq];
        float a1 = xsa[m * Cn + f * 8 + bq + 4];
        acc0.x += a0 * wa.x; acc0.y += a0 * wa.y; acc0.z += a0 * wa.z; acc0.w += a0 * wa.w;
        acc1.x += a1 * wa.x; acc1.y += a1 * wa.y; acc1.z += a1 * wa.z; acc1.w += a1 * wa.w;
        float4 wb = *(const float4*)&Wb[f * 64 + fo];
        float b0 = xsb[m * Cn + f * 8 + bq];
        float b1 = xsb[m * Cn + f * 8 + bq + 4];
        acc0.x += b0 * wb.x; acc0.y += b0 * wb.y; acc0.z += b0 * wb.z; acc0.w += b0 * wb.w;
        acc1.x += b1 * wb.x; acc1.y += b1 * wb.y; acc1.z += b1 * wb.z; acc1.w += b1 * wb.w;
    }

    size_t o0 = (((size_t)bq * Mn) + (m0 + m)) * FOUTn + fo;
    size_t o1 = (((size_t)(bq + 4) * Mn) + (m0 + m)) * FOUTn + fo;
    float4* out4_0 = (float4*)&out[o0];
    float4* out4_1 = (float4*)&out[o1];
    if (accum) {
        float4 c0 = *out4_0, c1 = *out4_1;
        acc0.x += c0.x; acc0.y += c0.y; acc0.z += c0.z; acc0.w += c0.w;
        acc1.x += c1.x; acc1.y += c1.y; acc1.z += c1.z; acc1.w += c1.w;
    }
    *out4_0 = acc0;
    *out4_1 = acc1;
}

// ---------------- launch ----------------

extern "C" void kernel_launch(void* const* d_in, const int* in_sizes, int n_in,
                              void* d_out, int out_size, void* d_ws, size_t ws_size,
                              hipStream_t stream) {
    const float* x         = (const float*)d_in[0];
    const float* edge_vals = (const float*)d_in[1];
    const float* W         = (const float*)d_in[2];
    const int*   edge_rows = (const int*)d_in[3];
    const int*   edge_cols = (const int*)d_in[4];
    float* out = (float*)d_out;

    char* ws = (char*)d_ws;
    size_t bufBytes = (size_t)Mn * Cn * sizeof(float);   // 81.92 MB each
    float* buf0 = (float*)(ws);
    float* buf1 = (float*)(ws + bufBytes);
    float* buf2 = (float*)(ws + 2 * bufBytes);
    int*   rowptr  = (int*)(ws + 3 * bufBytes);
    int*   fill    = rowptr + (Mn + 1);
    int*   csr_col = fill + Mn;
    float* csr_val = (float*)(csr_col + NNZn);

    // CSR build (every call; ws is re-poisoned by harness)
    hipMemsetAsync(fill, 0, Mn * sizeof(int), stream);
    k_hist<<<(NNZn + 255) / 256, 256, 0, stream>>>(edge_rows, fill);
    k_scan<<<1, 1024, 0, stream>>>(fill, rowptr);
    hipMemsetAsync(fill, 0, Mn * sizeof(int), stream);
    k_scatter<<<(NNZn + 255) / 256, 256, 0, stream>>>(edge_rows, edge_cols, edge_vals,
                                                      rowptr, fill, csr_col, csr_val);

    // x0 = transpose(x) -> buf0
    k_transpose<<<Mn, 512, 0, stream>>>(x, buf0);

    // x1 -> buf1 ; out = X0*W0 + X1*W1
    k_spmm<<<Mn, 128, 0, stream>>>((const float4*)buf0, (const float4*)buf0,
                                   (float4*)buf1, rowptr, csr_col, csr_val, 1);
    k_gemm2<<<Mn / 4, 256, 0, stream>>>(buf0, buf1, W, out, 0, 1, 0);

    // x2 -> buf2 ; x3 -> buf0 ; out += X2*W2 + X3*W3
    k_spmm<<<Mn, 128, 0, stream>>>((const float4*)buf1, (const float4*)buf0,
                                   (float4*)buf2, rowptr, csr_col, csr_val, 0);
    k_spmm<<<Mn, 128, 0, stream>>>((const float4*)buf2, (const float4*)buf1,
                                   (float4*)buf0, rowptr, csr_col, csr_val, 0);
    k_gemm2<<<Mn / 4, 256, 0, stream>>>(buf2, buf0, W, out, 2, 3, 1);

    // x4 -> buf1 ; x5 -> buf2 ; out += X4*W4 + X5*W5
    k_spmm<<<Mn, 128, 0, stream>>>((const float4*)buf0, (const float4*)buf2,
                                   (float4*)buf1, rowptr, csr_col, csr_val, 0);
    k_spmm<<<Mn, 128, 0, stream>>>((const float4*)buf1, (const float4*)buf0,
                                   (float4*)buf2, rowptr, csr_col, csr_val, 0);
    k_gemm2<<<Mn / 4, 256, 0, stream>>>(buf1, buf2, W, out, 4, 5, 1);
}

// Round 2
// 1291.789 us; speedup vs baseline: 1.0215x; 1.0215x over previous
//
#include <hip/hip_runtime.h>

// Problem constants (MeshConv: B=8, M=40000, FIN=64, K=6, FOUT=64, NNZ=320000)
#define Mn    40000
#define Bn    8
#define FINn  64
#define Kn    6
#define FOUTn 64
#define NNZn  320000
#define Cn    512   // FIN*B columns per Chebyshev level; layout c = b*64 + f

typedef __attribute__((ext_vector_type(8))) short short8;   // 8 bf16 (4 VGPRs)
typedef __attribute__((ext_vector_type(4))) float floatx4;  // MFMA accumulator

__device__ __forceinline__ ushort f2bf(float f) {
    unsigned u = __float_as_uint(f);
    u = (u + 0x7FFFu + ((u >> 16) & 1u)) >> 16;   // round-to-nearest-even
    return (ushort)u;
}

// ---------------- CSR build ----------------

__global__ __launch_bounds__(256) void k_hist(const int* __restrict__ rows,
                                              int* __restrict__ cnt) {
    int e = blockIdx.x * 256 + threadIdx.x;
    if (e < NNZn) atomicAdd(&cnt[rows[e]], 1);
}

__global__ __launch_bounds__(1024) void k_scan(const int* __restrict__ cnt,
                                               int* __restrict__ rowptr) {
    __shared__ int tmp[1024];
    __shared__ int carry_s;
    int tid = threadIdx.x;
    if (tid == 0) carry_s = 0;
    __syncthreads();
    for (int base = 0; base < Mn; base += 1024) {
        int i = base + tid;
        int v = (i < Mn) ? cnt[i] : 0;
        tmp[tid] = v;
        __syncthreads();
        for (int off = 1; off < 1024; off <<= 1) {
            int t = (tid >= off) ? tmp[tid - off] : 0;
            __syncthreads();
            tmp[tid] += t;
            __syncthreads();
        }
        if (i < Mn) rowptr[i] = carry_s + tmp[tid] - v;   // exclusive
        __syncthreads();
        if (tid == 0) carry_s += tmp[1023];
        __syncthreads();
    }
    if (tid == 0) rowptr[Mn] = carry_s;
}

__global__ __launch_bounds__(256) void k_scatter(const int* __restrict__ rows,
                                                 const int* __restrict__ cols,
                                                 const float* __restrict__ vals,
                                                 const int* __restrict__ rowptr,
                                                 int* __restrict__ fill,
                                                 int* __restrict__ csr_col,
                                                 float* __restrict__ csr_val) {
    int e = blockIdx.x * 256 + threadIdx.x;
    if (e < NNZn) {
        int r = rows[e];
        int p = rowptr[r] + atomicAdd(&fill[r], 1);
        csr_col[p] = cols[e];
        csr_val[p] = vals[e];
    }
}

// ---------------- x -> x0: x0[m, b*64+f] = x[b,m,f] (+ bf16 copy) ----------------

__global__ __launch_bounds__(512) void k_transpose(const float* __restrict__ x,
                                                   float* __restrict__ x0,
                                                   ushort* __restrict__ x0b) {
    int m = blockIdx.x, t = threadIdx.x;       // t = b*64 + f
    int b = t >> 6, f = t & 63;
    float v = x[((size_t)b * Mn + m) * 64 + f];        // coalesced per wave
    x0[(size_t)m * Cn + t] = v;                        // coalesced
    if (x0b) x0b[(size_t)m * Cn + t] = f2bf(v);
}

// ---------------- SpMM + Chebyshev recurrence ----------------
// acc = (L - I) xc ; xn = first ? acc : 2*acc - xp ; also store bf16(xn)

__global__ __launch_bounds__(128) void k_spmm(const float4* __restrict__ xc,
                                              const float4* __restrict__ xp,
                                              float4* __restrict__ xn,
                                              ushort* __restrict__ xnb,
                                              const int* __restrict__ rowptr,
                                              const int* __restrict__ csr_col,
                                              const float* __restrict__ csr_val,
                                              int first) {
    int m = blockIdx.x, t = threadIdx.x;   // 128 threads x float4 = 512 floats
    float4 v = xc[(size_t)m * 128 + t];
    float4 acc = make_float4(-v.x, -v.y, -v.z, -v.w);
    int beg = rowptr[m], end = rowptr[m + 1];
    for (int e = beg; e < end; ++e) {
        float val = csr_val[e];
        float4 g = xc[(size_t)csr_col[e] * 128 + t];
        acc.x += val * g.x; acc.y += val * g.y;
        acc.z += val * g.z; acc.w += val * g.w;
    }
    if (!first) {
        float4 p = xp[(size_t)m * 128 + t];
        acc.x = 2.f * acc.x - p.x; acc.y = 2.f * acc.y - p.y;
        acc.z = 2.f * acc.z - p.z; acc.w = 2.f * acc.w - p.w;
    }
    xn[(size_t)m * 128 + t] = acc;
    if (xnb) {
        ushort4 h;
        h.x = f2bf(acc.x); h.y = f2bf(acc.y); h.z = f2bf(acc.z); h.w = f2bf(acc.w);
        *(ushort4*)&xnb[(size_t)m * Cn + t * 4] = h;
    }
}

// ---------------- W -> MFMA B-fragment pre-swizzle ----------------
// Wfrag[((kk*4 + n)*64 + lane)*8 + j] = bf16( W[(f*6+lev)*64 + fo] )
//   kk = global K-chunk (0..11), lev = kk>>1, f = (kk&1)*32 + (lane>>4)*8 + j,
//   fo = n*16 + (lane&15)

__global__ __launch_bounds__(256) void k_wfrag(const float* __restrict__ W,
                                               ushort* __restrict__ wfrag) {
    int idx = blockIdx.x * 256 + threadIdx.x;   // 12*4*64*8 = 24576
    if (idx >= 12 * 4 * 64 * 8) return;
    int j    = idx & 7;
    int lane = (idx >> 3) & 63;
    int n    = (idx >> 9) & 3;
    int kk   = idx >> 11;
    int k    = (lane >> 4) * 8 + j;
    int lev  = kk >> 1;
    int f    = (kk & 1) * 32 + k;
    int fo   = n * 16 + (lane & 15);
    wfrag[idx] = f2bf(W[(f * Kn + lev) * FOUTn + fo]);
}

// ---------------- MFMA projection GEMM ----------------
// out[b, m, fo] (+)= sum over chunks: A[m, b*64+f] * W'[k][fo]
// Block: 256 thr (4 waves), tile 64 m-rows x 64 fo, one b per block.
// A tile staged in LDS (padded stride 40 ushorts to kill bank conflicts).

__global__ __launch_bounds__(256) void k_gemm_mfma(const ushort* __restrict__ xb,
                                                   const ushort* __restrict__ wfrag,
                                                   float* __restrict__ out,
                                                   int lev_base, int nlev, int accum) {
    __shared__ __align__(16) ushort As[64 * 40];   // 64 rows x 32 k, +8 pad
    int t    = threadIdx.x;
    int wv   = t >> 6;
    int lane = t & 63;
    int q    = lane >> 4, r = lane & 15;
    int b    = blockIdx.x & 7;
    int m0   = (blockIdx.x >> 3) * 64;

    floatx4 acc[4];
    acc[0] = (floatx4)0.f; acc[1] = (floatx4)0.f;
    acc[2] = (floatx4)0.f; acc[3] = (floatx4)0.f;

    int srow = t >> 2, spart = t & 3;   // staging: 64 rows x 4 x 16B
    int chunks = nlev * 2;
    for (int kk = 0; kk < chunks; ++kk) {
        int slot = kk >> 1;
        int f0   = (kk & 1) * 32;
        const ushort* src = xb + (size_t)slot * Mn * Cn
                          + (size_t)(m0 + srow) * Cn + b * 64 + f0 + spart * 8;
        uint4 v = *(const uint4*)src;
        __syncthreads();                       // prior chunk's reads complete
        *(uint4*)&As[srow * 40 + spart * 8] = v;
        __syncthreads();

        short8 af = *(const short8*)&As[(wv * 16 + r) * 40 + q * 8];
        int kkg = lev_base * 2 + kk;
        const ushort* wf = wfrag + ((size_t)(kkg * 4) * 64 + lane) * 8;
        acc[0] = __builtin_amdgcn_mfma_f32_16x16x32_bf16(af, *(const short8*)(wf),        acc[0], 0, 0, 0);
        acc[1] = __builtin_amdgcn_mfma_f32_16x16x32_bf16(af, *(const short8*)(wf + 512),  acc[1], 0, 0, 0);
        acc[2] = __builtin_amdgcn_mfma_f32_16x16x32_bf16(af, *(const short8*)(wf + 1024), acc[2], 0, 0, 0);
        acc[3] = __builtin_amdgcn_mfma_f32_16x16x32_bf16(af, *(const short8*)(wf + 1536), acc[3], 0, 0, 0);
    }

    // C/D layout: col = lane&15, row = (lane>>4)*4 + reg
    size_t obase = ((size_t)b * Mn + m0 + wv * 16) * FOUTn;
    for (int n = 0; n < 4; ++n) {
        for (int reg = 0; reg < 4; ++reg) {
            int row = q * 4 + reg;
            size_t o = obase + (size_t)row * FOUTn + n * 16 + r;
            float val = acc[n][reg];
            if (accum) val += out[o];
            out[o] = val;
        }
    }
}

// ---------------- legacy fp32 paired GEMM (fallback plan C) ----------------

__global__ __launch_bounds__(256) void k_gemm2(const float* __restrict__ xa,
                                               const float* __restrict__ xb,
                                               const float* __restrict__ W,
                                               float* __restrict__ out,
                                               int ka, int kb, int accum) {
    __shared__ __align__(16) float Wa[64 * 64];
    __shared__ __align__(16) float Wb[64 * 64];
    __shared__ __align__(16) float xsa[4 * Cn];
    __shared__ __align__(16) float xsb[4 * Cn];
    int t = threadIdx.x;
    size_t m0 = (size_t)blockIdx.x * 4;
    for (int i = t; i < 4096; i += 256) {
        int f = i >> 6, fo = i & 63;
        Wa[i] = W[(f * Kn + ka) * FOUTn + fo];
        Wb[i] = W[(f * Kn + kb) * FOUTn + fo];
    }
    for (int i = t; i < 4 * Cn; i += 256) {
        xsa[i] = xa[m0 * Cn + i];
        xsb[i] = xb[m0 * Cn + i];
    }
    __syncthreads();
    // layout now c = b*64+f : x[m, b*64+f]
    int fo  = (t & 15) * 4;
    int idx = t >> 4;
    int m   = idx & 3;
    int bq  = idx >> 2;
    float4 acc0 = make_float4(0.f, 0.f, 0.f, 0.f);
    float4 acc1 = make_float4(0.f, 0.f, 0.f, 0.f);
    for (int f = 0; f < 64; ++f) {
        float4 wa = *(const float4*)&Wa[f * 64 + fo];
        float a0 = xsa[m * Cn + bq * 64 + f];
        float a1 = xsa[m * Cn + (bq + 4) * 64 + f];
        acc0.x += a0 * wa.x; acc0.y += a0 * wa.y; acc0.z += a0 * wa.z; acc0.w += a0 * wa.w;
        acc1.x += a1 * wa.x; acc1.y += a1 * wa.y; acc1.z += a1 * wa.z; acc1.w += a1 * wa.w;
        float4 wb = *(const float4*)&Wb[f * 64 + fo];
        float b0 = xsb[m * Cn + bq * 64 + f];
        float b1 = xsb[m * Cn + (bq + 4) * 64 + f];
        acc0.x += b0 * wb.x; acc0.y += b0 * wb.y; acc0.z += b0 * wb.z; acc0.w += b0 * wb.w;
        acc1.x += b1 * wb.x; acc1.y += b1 * wb.y; acc1.z += b1 * wb.z; acc1.w += b1 * wb.w;
    }
    size_t o0 = (((size_t)bq * Mn) + (m0 + m)) * FOUTn + fo;
    size_t o1 = (((size_t)(bq + 4) * Mn) + (m0 + m)) * FOUTn + fo;
    float4* out4_0 = (float4*)&out[o0];
    float4* out4_1 = (float4*)&out[o1];
    if (accum) {
        float4 c0 = *out4_0, c1 = *out4_1;
        acc0.x += c0.x; acc0.y += c0.y; acc0.z += c0.z; acc0.w += c0.w;
        acc1.x += c1.x; acc1.y += c1.y; acc1.z += c1.z; acc1.w += c1.w;
    }
    *out4_0 = acc0;
    *out4_1 = acc1;
}

// ---------------- launch ----------------

extern "C" void kernel_launch(void* const* d_in, const int* in_sizes, int n_in,
                              void* d_out, int out_size, void* d_ws, size_t ws_size,
                              hipStream_t stream) {
    const float* x         = (const float*)d_in[0];
    const float* edge_vals = (const float*)d_in[1];
    const float* W         = (const float*)d_in[2];
    const int*   edge_rows = (const int*)d_in[3];
    const int*   edge_cols = (const int*)d_in[4];
    float* out = (float*)d_out;

    char* ws = (char*)d_ws;
    const size_t bufB = (size_t)Mn * Cn * sizeof(float);   // 81.92 MB fp32 level
    const size_t bufH = (size_t)Mn * Cn * sizeof(ushort);  // 40.96 MB bf16 level
    const size_t wfB  = 12 * 4 * 64 * 8 * sizeof(ushort);  // 48 KB
    const size_t csrB = (size_t)(Mn + 1 + Mn + NNZn) * 4 + (size_t)NNZn * 4;

    // plan selection by ws capacity
    int nslots;   // bf16 level slots: 6 (plan A), 2 (plan B), 0 (plan C)
    if (ws_size >= 3 * bufB + 6 * bufH + wfB + csrB)      nslots = 6;
    else if (ws_size >= 3 * bufB + 2 * bufH + wfB + csrB) nslots = 2;
    else                                                  nslots = 0;

    float*  buf0 = (float*)(ws);
    float*  buf1 = (float*)(ws + bufB);
    float*  buf2 = (float*)(ws + 2 * bufB);
    ushort* xbb  = (ushort*)(ws + 3 * bufB);
    ushort* wfr  = (ushort*)(ws + 3 * bufB + nslots * bufH);
    int*    rowptr  = (int*)(ws + 3 * bufB + nslots * bufH + (nslots ? wfB : 0));
    int*    fill    = rowptr + (Mn + 1);
    int*    csr_col = fill + Mn;
    float*  csr_val = (float*)(csr_col + NNZn);

    // CSR build (every call)
    hipMemsetAsync(fill, 0, Mn * sizeof(int), stream);
    k_hist<<<(NNZn + 255) / 256, 256, 0, stream>>>(edge_rows, fill);
    k_scan<<<1, 1024, 0, stream>>>(fill, rowptr);
    hipMemsetAsync(fill, 0, Mn * sizeof(int), stream);
    k_scatter<<<(NNZn + 255) / 256, 256, 0, stream>>>(edge_rows, edge_cols, edge_vals,
                                                      rowptr, fill, csr_col, csr_val);

    ushort* slotp[6];
    for (int l = 0; l < 6; ++l)
        slotp[l] = nslots ? (xbb + (size_t)(nslots == 6 ? l : (l & 1)) * Mn * Cn) : nullptr;

    if (nslots) k_wfrag<<<96, 256, 0, stream>>>(W, wfr);

    // x0
    k_transpose<<<Mn, 512, 0, stream>>>(x, buf0, slotp[0]);
    // x1
    k_spmm<<<Mn, 128, 0, stream>>>((const float4*)buf0, (const float4*)buf0,
                                   (float4*)buf1, slotp[1], rowptr, csr_col, csr_val, 1);
    if (nslots == 2)
        k_gemm_mfma<<<(Mn / 64) * 8, 256, 0, stream>>>(xbb, wfr, out, 0, 2, 0);
    else if (nslots == 0)
        k_gemm2<<<Mn / 4, 256, 0, stream>>>(buf0, buf1, W, out, 0, 1, 0);
    // x2, x3
    k_spmm<<<Mn, 128, 0, stream>>>((const float4*)buf1, (const float4*)buf0,
                                   (float4*)buf2, slotp[2], rowptr, csr_col, csr_val, 0);
    k_spmm<<<Mn, 128, 0, stream>>>((const float4*)buf2, (const float4*)buf1,
                                   (float4*)buf0, slotp[3], rowptr, csr_col, csr_val, 0);
    if (nslots == 2)
        k_gemm_mfma<<<(Mn / 64) * 8, 256, 0, stream>>>(xbb, wfr, out, 2, 2, 1);
    else if (nslots == 0)
        k_gemm2<<<Mn / 4, 256, 0, stream>>>(buf2, buf0, W, out, 2, 3, 1);
    // x4, x5
    k_spmm<<<Mn, 128, 0, stream>>>((const float4*)buf0, (const float4*)buf2,
                                   (float4*)buf1, slotp[4], rowptr, csr_col, csr_val, 0);
    k_spmm<<<Mn, 128, 0, stream>>>((const float4*)buf1, (const float4*)buf0,
                                   (float4*)buf2, slotp[5], rowptr, csr_col, csr_val, 0);
    if (nslots == 6)
        k_gemm_mfma<<<(Mn / 64) * 8, 256, 0, stream>>>(xbb, wfr, out, 0, 6, 0);
    else if (nslots == 2)
        k_gemm_mfma<<<(Mn / 64) * 8, 256, 0, stream>>>(xbb, wfr, out, 4, 2, 1);
    else
        k_gemm2<<<Mn / 4, 256, 0, stream>>>(buf1, buf2, W, out, 4, 5, 1);
}

// Round 3
// 1046.110 us; speedup vs baseline: 1.2614x; 1.2348x over previous
//
#include <hip/hip_runtime.h>

// Problem constants (MeshConv: B=8, M=40000, FIN=64, K=6, FOUT=64, NNZ=320000)
#define Mn    40000
#define Bn    8
#define FINn  64
#define Kn    6
#define FOUTn 64
#define NNZn  320000
#define Cn    512   // FIN*B columns per Chebyshev level; layout c = b*64 + f

typedef __attribute__((ext_vector_type(8))) short short8;   // 8 bf16 (4 VGPRs)
typedef __attribute__((ext_vector_type(4))) float floatx4;  // MFMA accumulator

__device__ __forceinline__ ushort f2bf(float f) {
    unsigned u = __float_as_uint(f);
    u = (u + 0x7FFFu + ((u >> 16) & 1u)) >> 16;   // round-to-nearest-even
    return (ushort)u;
}

// ---------------- CSR build ----------------

__global__ __launch_bounds__(256) void k_hist(const int* __restrict__ rows,
                                              int* __restrict__ cnt) {
    int e = blockIdx.x * 256 + threadIdx.x;
    if (e < NNZn) atomicAdd(&cnt[rows[e]], 1);
}

__global__ __launch_bounds__(1024) void k_scan(const int* __restrict__ cnt,
                                               int* __restrict__ rowptr) {
    __shared__ int tmp[1024];
    __shared__ int carry_s;
    int tid = threadIdx.x;
    if (tid == 0) carry_s = 0;
    __syncthreads();
    for (int base = 0; base < Mn; base += 1024) {
        int i = base + tid;
        int v = (i < Mn) ? cnt[i] : 0;
        tmp[tid] = v;
        __syncthreads();
        for (int off = 1; off < 1024; off <<= 1) {
            int t = (tid >= off) ? tmp[tid - off] : 0;
            __syncthreads();
            tmp[tid] += t;
            __syncthreads();
        }
        if (i < Mn) rowptr[i] = carry_s + tmp[tid] - v;   // exclusive
        __syncthreads();
        if (tid == 0) carry_s += tmp[1023];
        __syncthreads();
    }
    if (tid == 0) rowptr[Mn] = carry_s;
}

__global__ __launch_bounds__(256) void k_scatter(const int* __restrict__ rows,
                                                 const int* __restrict__ cols,
                                                 const float* __restrict__ vals,
                                                 const int* __restrict__ rowptr,
                                                 int* __restrict__ fill,
                                                 int2* __restrict__ csr) {
    int e = blockIdx.x * 256 + threadIdx.x;
    if (e < NNZn) {
        int r = rows[e];
        int p = rowptr[r] + atomicAdd(&fill[r], 1);
        int2 cv; cv.x = cols[e]; cv.y = __float_as_int(vals[e]);
        csr[p] = cv;
    }
}

// ---------------- x -> x0: x0[m, b*64+f] = x[b,m,f] (+ bf16 copy) ----------------

__global__ __launch_bounds__(512) void k_transpose(const float* __restrict__ x,
                                                   float* __restrict__ x0,
                                                   ushort* __restrict__ x0b) {
    int m = blockIdx.x, t = threadIdx.x;       // t = b*64 + f
    int b = t >> 6, f = t & 63;
    float v = x[((size_t)b * Mn + m) * 64 + f];        // coalesced per wave
    x0[(size_t)m * Cn + t] = v;                        // coalesced
    if (x0b) x0b[(size_t)m * Cn + t] = f2bf(v);
}

// ---------------- SpMM + Chebyshev recurrence ----------------
// acc = (L - I) xc ; xn = first ? acc : 2*acc - xp ; also store bf16(xn).
// Caller may pass xn == xp (in-place: xp[m,c] read once, then overwritten).
// 4 rows/block, 64 lanes/row, 8 floats/lane; edge loop unrolled x2 -> 4
// independent dwordx4 gathers in flight.

__global__ __launch_bounds__(256) void k_spmm(const float4* __restrict__ xc,
                                              const float4* __restrict__ xp,
                                              float4* __restrict__ xn,
                                              ushort* __restrict__ xnb,
                                              const int* __restrict__ rowptr,
                                              const int2* __restrict__ csr,
                                              int first) {
    int t = threadIdx.x;
    int lane = t & 63;
    int m = blockIdx.x * 4 + (t >> 6);
    size_t rb = (size_t)m * 128;
    float4 v0 = xc[rb + lane];
    float4 v1 = xc[rb + 64 + lane];
    float4 a0 = make_float4(-v0.x, -v0.y, -v0.z, -v0.w);
    float4 a1 = make_float4(-v1.x, -v1.y, -v1.z, -v1.w);
    int e = rowptr[m], end = rowptr[m + 1];
    for (; e + 2 <= end; e += 2) {
        int2 cv0 = csr[e];
        int2 cv1 = csr[e + 1];
        float w0 = __int_as_float(cv0.y);
        float w1 = __int_as_float(cv1.y);
        const float4* r0 = xc + (size_t)cv0.x * 128;
        const float4* r1 = xc + (size_t)cv1.x * 128;
        float4 g00 = r0[lane], g01 = r0[64 + lane];
        float4 g10 = r1[lane], g11 = r1[64 + lane];
        a0.x += w0 * g00.x; a0.y += w0 * g00.y; a0.z += w0 * g00.z; a0.w += w0 * g00.w;
        a1.x += w0 * g01.x; a1.y += w0 * g01.y; a1.z += w0 * g01.z; a1.w += w0 * g01.w;
        a0.x += w1 * g10.x; a0.y += w1 * g10.y; a0.z += w1 * g10.z; a0.w += w1 * g10.w;
        a1.x += w1 * g11.x; a1.y += w1 * g11.y; a1.z += w1 * g11.z; a1.w += w1 * g11.w;
    }
    if (e < end) {
        int2 cv = csr[e];
        float w = __int_as_float(cv.y);
        const float4* r = xc + (size_t)cv.x * 128;
        float4 g0 = r[lane], g1 = r[64 + lane];
        a0.x += w * g0.x; a0.y += w * g0.y; a0.z += w * g0.z; a0.w += w * g0.w;
        a1.x += w * g1.x; a1.y += w * g1.y; a1.z += w * g1.z; a1.w += w * g1.w;
    }
    if (!first) {
        float4 p0 = xp[rb + lane];
        float4 p1 = xp[rb + 64 + lane];
        a0.x = 2.f * a0.x - p0.x; a0.y = 2.f * a0.y - p0.y;
        a0.z = 2.f * a0.z - p0.z; a0.w = 2.f * a0.w - p0.w;
        a1.x = 2.f * a1.x - p1.x; a1.y = 2.f * a1.y - p1.y;
        a1.z = 2.f * a1.z - p1.z; a1.w = 2.f * a1.w - p1.w;
    }
    xn[rb + lane] = a0;
    xn[rb + 64 + lane] = a1;
    if (xnb) {
        ushort4 h0, h1;
        h0.x = f2bf(a0.x); h0.y = f2bf(a0.y); h0.z = f2bf(a0.z); h0.w = f2bf(a0.w);
        h1.x = f2bf(a1.x); h1.y = f2bf(a1.y); h1.z = f2bf(a1.z); h1.w = f2bf(a1.w);
        *(ushort4*)&xnb[(size_t)m * Cn + lane * 4] = h0;
        *(ushort4*)&xnb[(size_t)m * Cn + 256 + lane * 4] = h1;
    }
}

// ---------------- W -> MFMA B-fragment pre-swizzle ----------------
// Wfrag[((kk*4 + n)*64 + lane)*8 + j] = bf16( W[(f*6+lev)*64 + fo] )
//   kk = global K-chunk (0..11), lev = kk>>1, f = (kk&1)*32 + (lane>>4)*8 + j,
//   fo = n*16 + (lane&15)

__global__ __launch_bounds__(256) void k_wfrag(const float* __restrict__ W,
                                               ushort* __restrict__ wfrag) {
    int idx = blockIdx.x * 256 + threadIdx.x;   // 12*4*64*8 = 24576
    if (idx >= 12 * 4 * 64 * 8) return;
    int j    = idx & 7;
    int lane = (idx >> 3) & 63;
    int n    = (idx >> 9) & 3;
    int kk   = idx >> 11;
    int k    = (lane >> 4) * 8 + j;
    int lev  = kk >> 1;
    int f    = (kk & 1) * 32 + k;
    int fo   = n * 16 + (lane & 15);
    wfrag[idx] = f2bf(W[(f * Kn + lev) * FOUTn + fo]);
}

// ---------------- MFMA projection GEMM ----------------
// out[b, m, fo] (+)= sum over levels lev_base..lev_base+nlev-1, f:
//   Xlev[m, b*64+f] * W[(f*6+lev)*64+fo]
// Block: 256 thr (4 waves), tile 64 m-rows x 64 fo, one b per block.
// Level slot in xb = level % nslots (rotation must match host ordering).

__global__ __launch_bounds__(256) void k_gemm_mfma(const ushort* __restrict__ xb,
                                                   const ushort* __restrict__ wfrag,
                                                   float* __restrict__ out,
                                                   int lev_base, int nlev,
                                                   int nslots, int accum) {
    __shared__ __align__(16) ushort As[64 * 40];   // 64 rows x 32 k, +8 pad
    int t    = threadIdx.x;
    int wv   = t >> 6;
    int lane = t & 63;
    int q    = lane >> 4, r = lane & 15;
    int b    = blockIdx.x & 7;
    int m0   = (blockIdx.x >> 3) * 64;

    floatx4 acc[4];
    acc[0] = (floatx4)0.f; acc[1] = (floatx4)0.f;
    acc[2] = (floatx4)0.f; acc[3] = (floatx4)0.f;

    int srow = t >> 2, spart = t & 3;   // staging: 64 rows x 4 x 16B
    int chunks = nlev * 2;
    for (int kk = 0; kk < chunks; ++kk) {
        int lev  = lev_base + (kk >> 1);
        int slot = lev % nslots;
        int f0   = (kk & 1) * 32;
        const ushort* src = xb + (size_t)slot * Mn * Cn
                          + (size_t)(m0 + srow) * Cn + b * 64 + f0 + spart * 8;
        uint4 v = *(const uint4*)src;
        __syncthreads();                       // prior chunk's LDS reads done
        *(uint4*)&As[srow * 40 + spart * 8] = v;
        __syncthreads();

        short8 af = *(const short8*)&As[(wv * 16 + r) * 40 + q * 8];
        int kkg = lev * 2 + (kk & 1);
        const ushort* wf = wfrag + ((size_t)(kkg * 4) * 64 + lane) * 8;
        acc[0] = __builtin_amdgcn_mfma_f32_16x16x32_bf16(af, *(const short8*)(wf),        acc[0], 0, 0, 0);
        acc[1] = __builtin_amdgcn_mfma_f32_16x16x32_bf16(af, *(const short8*)(wf + 512),  acc[1], 0, 0, 0);
        acc[2] = __builtin_amdgcn_mfma_f32_16x16x32_bf16(af, *(const short8*)(wf + 1024), acc[2], 0, 0, 0);
        acc[3] = __builtin_amdgcn_mfma_f32_16x16x32_bf16(af, *(const short8*)(wf + 1536), acc[3], 0, 0, 0);
    }

    // C/D layout: col = lane&15, row = (lane>>4)*4 + reg
    size_t obase = ((size_t)b * Mn + m0 + wv * 16) * FOUTn;
    for (int n = 0; n < 4; ++n) {
        for (int reg = 0; reg < 4; ++reg) {
            int row = q * 4 + reg;
            size_t o = obase + (size_t)row * FOUTn + n * 16 + r;
            float val = acc[n][reg];
            if (accum) val += out[o];
            out[o] = val;
        }
    }
}

// ---------------- legacy fp32 paired GEMM (fallback) ----------------

__global__ __launch_bounds__(256) void k_gemm2(const float* __restrict__ xa,
                                               const float* __restrict__ xb,
                                               const float* __restrict__ W,
                                               float* __restrict__ out,
                                               int ka, int kb, int accum) {
    __shared__ __align__(16) float Wa[64 * 64];
    __shared__ __align__(16) float Wb[64 * 64];
    __shared__ __align__(16) float xsa[4 * Cn];
    __shared__ __align__(16) float xsb[4 * Cn];
    int t = threadIdx.x;
    size_t m0 = (size_t)blockIdx.x * 4;
    for (int i = t; i < 4096; i += 256) {
        int f = i >> 6, fo = i & 63;
        Wa[i] = W[(f * Kn + ka) * FOUTn + fo];
        Wb[i] = W[(f * Kn + kb) * FOUTn + fo];
    }
    for (int i = t; i < 4 * Cn; i += 256) {
        xsa[i] = xa[m0 * Cn + i];
        xsb[i] = xb[m0 * Cn + i];
    }
    __syncthreads();
    int fo  = (t & 15) * 4;
    int idx = t >> 4;
    int m   = idx & 3;
    int bq  = idx >> 2;
    float4 acc0 = make_float4(0.f, 0.f, 0.f, 0.f);
    float4 acc1 = make_float4(0.f, 0.f, 0.f, 0.f);
    for (int f = 0; f < 64; ++f) {
        float4 wa = *(const float4*)&Wa[f * 64 + fo];
        float a0 = xsa[m * Cn + bq * 64 + f];
        float a1 = xsa[m * Cn + (bq + 4) * 64 + f];
        acc0.x += a0 * wa.x; acc0.y += a0 * wa.y; acc0.z += a0 * wa.z; acc0.w += a0 * wa.w;
        acc1.x += a1 * wa.x; acc1.y += a1 * wa.y; acc1.z += a1 * wa.z; acc1.w += a1 * wa.w;
        float4 wb = *(const float4*)&Wb[f * 64 + fo];
        float b0 = xsb[m * Cn + bq * 64 + f];
        float b1 = xsb[m * Cn + (bq + 4) * 64 + f];
        acc0.x += b0 * wb.x; acc0.y += b0 * wb.y; acc0.z += b0 * wb.z; acc0.w += b0 * wb.w;
        acc1.x += b1 * wb.x; acc1.y += b1 * wb.y; acc1.z += b1 * wb.z; acc1.w += b1 * wb.w;
    }
    size_t o0 = (((size_t)bq * Mn) + (m0 + m)) * FOUTn + fo;
    size_t o1 = (((size_t)(bq + 4) * Mn) + (m0 + m)) * FOUTn + fo;
    float4* out4_0 = (float4*)&out[o0];
    float4* out4_1 = (float4*)&out[o1];
    if (accum) {
        float4 c0 = *out4_0, c1 = *out4_1;
        acc0.x += c0.x; acc0.y += c0.y; acc0.z += c0.z; acc0.w += c0.w;
        acc1.x += c1.x; acc1.y += c1.y; acc1.z += c1.z; acc1.w += c1.w;
    }
    *out4_0 = acc0;
    *out4_1 = acc1;
}

// ---------------- launch ----------------

extern "C" void kernel_launch(void* const* d_in, const int* in_sizes, int n_in,
                              void* d_out, int out_size, void* d_ws, size_t ws_size,
                              hipStream_t stream) {
    const float* x         = (const float*)d_in[0];
    const float* edge_vals = (const float*)d_in[1];
    const float* W         = (const float*)d_in[2];
    const int*   edge_rows = (const int*)d_in[3];
    const int*   edge_cols = (const int*)d_in[4];
    float* out = (float*)d_out;

    char* ws = (char*)d_ws;
    const size_t bufB = (size_t)Mn * Cn * sizeof(float);   // 81.92 MB fp32 level
    const size_t bufH = (size_t)Mn * Cn * sizeof(ushort);  // 40.96 MB bf16 level
    const size_t wfB  = 12 * 4 * 64 * 8 * sizeof(ushort);  // 48 KB
    const size_t csrB = (size_t)(Mn + 4 + Mn) * 4 + (size_t)NNZn * 8;  // ~3 MB

    // plan: 2 fp32 recurrence buffers (in-place xn->xp) + nslots bf16 levels
    int nslots;
    if      (ws_size >= 2 * bufB + 6 * bufH + wfB + csrB) nslots = 6;  // one GEMM
    else if (ws_size >= 2 * bufB + 3 * bufH + wfB + csrB) nslots = 3;  // two GEMMs
    else if (ws_size >= 2 * bufB + 2 * bufH + wfB + csrB) nslots = 2;  // three GEMMs
    else                                                  nslots = 0;  // fp32 fallback

    float*  buf0 = (float*)(ws);
    float*  buf1 = (float*)(ws + bufB);
    ushort* xbb  = (ushort*)(ws + 2 * bufB);
    ushort* wfr  = (ushort*)(ws + 2 * bufB + nslots * bufH);
    char*   csrbase = ws + 2 * bufB + nslots * bufH + (nslots ? wfB : 0);
    int*    rowptr  = (int*)csrbase;                 // Mn+4 ints (padded for align)
    int*    fill    = rowptr + (Mn + 4);
    int2*   csr     = (int2*)(fill + Mn);            // 8B-aligned by construction

    // CSR build (every call)
    hipMemsetAsync(fill, 0, Mn * sizeof(int), stream);
    k_hist<<<(NNZn + 255) / 256, 256, 0, stream>>>(edge_rows, fill);
    k_scan<<<1, 1024, 0, stream>>>(fill, rowptr);
    hipMemsetAsync(fill, 0, Mn * sizeof(int), stream);
    k_scatter<<<(NNZn + 255) / 256, 256, 0, stream>>>(edge_rows, edge_cols, edge_vals,
                                                      rowptr, fill, csr);

    ushort* slotp[6];
    for (int l = 0; l < 6; ++l)
        slotp[l] = nslots ? (xbb + (size_t)(l % nslots) * Mn * Cn) : nullptr;

    if (nslots) k_wfrag<<<96, 256, 0, stream>>>(W, wfr);

    const int spmm_grid = Mn / 4;
    const int gemm_grid = (Mn / 64) * 8;

    // x0 -> buf0 ; x1 = (L-I)x0 -> buf1
    k_transpose<<<Mn, 512, 0, stream>>>(x, buf0, slotp[0]);
    k_spmm<<<spmm_grid, 256, 0, stream>>>((const float4*)buf0, (const float4*)buf0,
                                          (float4*)buf1, slotp[1], rowptr, csr, 1);
    if (nslots == 2)
        k_gemm_mfma<<<gemm_grid, 256, 0, stream>>>(xbb, wfr, out, 0, 2, nslots, 0);
    else if (nslots == 0)
        k_gemm2<<<Mn / 4, 256, 0, stream>>>(buf0, buf1, W, out, 0, 1, 0);

    // x2 = 2(L-I)x1 - x0 -> buf0 (in place over x0) ; x3 -> buf1
    k_spmm<<<spmm_grid, 256, 0, stream>>>((const float4*)buf1, (const float4*)buf0,
                                          (float4*)buf0, slotp[2], rowptr, csr, 0);
    if (nslots == 3)
        k_gemm_mfma<<<gemm_grid, 256, 0, stream>>>(xbb, wfr, out, 0, 3, nslots, 0);
    k_spmm<<<spmm_grid, 256, 0, stream>>>((const float4*)buf0, (const float4*)buf1,
                                          (float4*)buf1, slotp[3], rowptr, csr, 0);
    if (nslots == 2)
        k_gemm_mfma<<<gemm_grid, 256, 0, stream>>>(xbb, wfr, out, 2, 2, nslots, 1);
    else if (nslots == 0)
        k_gemm2<<<Mn / 4, 256, 0, stream>>>(buf0, buf1, W, out, 2, 3, 1);

    // x4 -> buf0 ; x5 -> buf1
    k_spmm<<<spmm_grid, 256, 0, stream>>>((const float4*)buf1, (const float4*)buf0,
                                          (float4*)buf0, slotp[4], rowptr, csr, 0);
    k_spmm<<<spmm_grid, 256, 0, stream>>>((const float4*)buf0, (const float4*)buf1,
                                          (float4*)buf1, slotp[5], rowptr, csr, 0);
    if (nslots == 6)
        k_gemm_mfma<<<gemm_grid, 256, 0, stream>>>(xbb, wfr, out, 0, 6, nslots, 0);
    else if (nslots == 3)
        k_gemm_mfma<<<gemm_grid, 256, 0, stream>>>(xbb, wfr, out, 3, 3, nslots, 1);
    else if (nslots == 2)
        k_gemm_mfma<<<gemm_grid, 256, 0, stream>>>(xbb, wfr, out, 4, 2, nslots, 1);
    else
        k_gemm2<<<Mn / 4, 256, 0, stream>>>(buf0, buf1, W, out, 4, 5, 1);
}

// Round 4
// 816.304 us; speedup vs baseline: 1.6165x; 1.2815x over previous
//
#include <hip/hip_runtime.h>

// Problem constants (MeshConv: B=8, M=40000, FIN=64, K=6, FOUT=64, NNZ=320000)
#define Mn    40000
#define Bn    8
#define FINn  64
#define Kn    6
#define FOUTn 64
#define NNZn  320000
#define Cn    512   // FIN*B columns per Chebyshev level; layout c = b*64 + f

typedef __attribute__((ext_vector_type(8))) short short8;   // 8 bf16 (4 VGPRs)
typedef __attribute__((ext_vector_type(4))) float floatx4;  // MFMA accumulator

__device__ __forceinline__ ushort f2bf(float f) {
    unsigned u = __float_as_uint(f);
    u = (u + 0x7FFFu + ((u >> 16) & 1u)) >> 16;   // round-to-nearest-even
    return (ushort)u;
}

// ---------------- CSR build ----------------

__global__ __launch_bounds__(256) void k_hist(const int* __restrict__ rows,
                                              int* __restrict__ cnt) {
    int e = blockIdx.x * 256 + threadIdx.x;
    if (e < NNZn) atomicAdd(&cnt[rows[e]], 1);
}

// chunked scan: 1024 threads x 40 rows each; one 10-step LDS scan
__global__ __launch_bounds__(1024) void k_scan(const int* __restrict__ cnt,
                                               int* __restrict__ rowptr) {
    __shared__ int part[1024];
    int tid = threadIdx.x;
    int base = tid * 40;
    int s = 0;
    for (int i = 0; i < 40; ++i) {
        int r = base + i;
        if (r < Mn) s += cnt[r];
    }
    part[tid] = s;
    __syncthreads();
    for (int off = 1; off < 1024; off <<= 1) {
        int t = (tid >= off) ? part[tid - off] : 0;
        __syncthreads();
        part[tid] += t;
        __syncthreads();
    }
    int run = part[tid] - s;   // exclusive prefix of this chunk
    for (int i = 0; i < 40; ++i) {
        int r = base + i;
        if (r < Mn) { rowptr[r] = run; run += cnt[r]; }
    }
    if (tid == 1023) rowptr[Mn] = part[1023];
}

__global__ __launch_bounds__(256) void k_scatter(const int* __restrict__ rows,
                                                 const int* __restrict__ cols,
                                                 const float* __restrict__ vals,
                                                 const int* __restrict__ rowptr,
                                                 int* __restrict__ fill,
                                                 int2* __restrict__ csr) {
    int e = blockIdx.x * 256 + threadIdx.x;
    if (e < NNZn) {
        int r = rows[e];
        int p = rowptr[r] + atomicAdd(&fill[r], 1);
        int2 cv; cv.x = cols[e]; cv.y = __float_as_int(vals[e]);
        csr[p] = cv;
    }
}

// ---------------- x -> x0: x0[m, b*64+f] = x[b,m,f] (+ bf16 copy) ----------------

__global__ __launch_bounds__(512) void k_transpose(const float* __restrict__ x,
                                                   float* __restrict__ x0,
                                                   ushort* __restrict__ x0b) {
    int m = blockIdx.x, t = threadIdx.x;       // t = b*64 + f
    int b = t >> 6, f = t & 63;
    float v = x[((size_t)b * Mn + m) * 64 + f];        // coalesced per wave
    x0[(size_t)m * Cn + t] = v;                        // coalesced
    if (x0b) x0b[(size_t)m * Cn + t] = f2bf(v);
}

// ---------------- SpMM (bf16 gather) + Chebyshev recurrence ----------------
// acc = -xc_fp32[m] + sum val * bf16(xc)[col] ; xn = first ? acc : 2*acc - xp.
// One row per wave (64 lanes x 8 floats). Gather: one uint4 (8 bf16) per lane
// per edge, unrolled x4. Streams (xc, xp, xn) stay fp32; in-place xn==xp ok.

__device__ __forceinline__ void fma8(float* a, uint4 g, float w) {
    unsigned uu[4] = {g.x, g.y, g.z, g.w};
#pragma unroll
    for (int i = 0; i < 4; ++i) {
        float lo = __uint_as_float(uu[i] << 16);
        float hi = __uint_as_float(uu[i] & 0xFFFF0000u);
        a[2 * i]     += w * lo;
        a[2 * i + 1] += w * hi;
    }
}

__global__ __launch_bounds__(256) void k_spmm_bf(const float4* __restrict__ xc,
                                                 const float4* __restrict__ xp,
                                                 float4* __restrict__ xn,
                                                 ushort* __restrict__ xnb,
                                                 const ushort* __restrict__ gsrc,
                                                 const int* __restrict__ rowptr,
                                                 const int2* __restrict__ csr,
                                                 int first) {
    int t = threadIdx.x;
    int lane = t & 63;
    int m = blockIdx.x * 4 + (t >> 6);
    size_t rb = (size_t)m * 128;              // row base in float4 units
    float4 v0 = xc[rb + lane * 2];
    float4 v1 = xc[rb + lane * 2 + 1];
    float a[8];
    a[0] = -v0.x; a[1] = -v0.y; a[2] = -v0.z; a[3] = -v0.w;
    a[4] = -v1.x; a[5] = -v1.y; a[6] = -v1.z; a[7] = -v1.w;

    int e = rowptr[m], end = rowptr[m + 1];
    for (; e + 4 <= end; e += 4) {
        int2 cv0 = csr[e],     cv1 = csr[e + 1];
        int2 cv2 = csr[e + 2], cv3 = csr[e + 3];
        uint4 g0 = ((const uint4*)(gsrc + (size_t)cv0.x * Cn))[lane];
        uint4 g1 = ((const uint4*)(gsrc + (size_t)cv1.x * Cn))[lane];
        uint4 g2 = ((const uint4*)(gsrc + (size_t)cv2.x * Cn))[lane];
        uint4 g3 = ((const uint4*)(gsrc + (size_t)cv3.x * Cn))[lane];
        fma8(a, g0, __int_as_float(cv0.y));
        fma8(a, g1, __int_as_float(cv1.y));
        fma8(a, g2, __int_as_float(cv2.y));
        fma8(a, g3, __int_as_float(cv3.y));
    }
    for (; e < end; ++e) {
        int2 cv = csr[e];
        uint4 g = ((const uint4*)(gsrc + (size_t)cv.x * Cn))[lane];
        fma8(a, g, __int_as_float(cv.y));
    }

    if (!first) {
        float4 p0 = xp[rb + lane * 2];
        float4 p1 = xp[rb + lane * 2 + 1];
        a[0] = 2.f * a[0] - p0.x; a[1] = 2.f * a[1] - p0.y;
        a[2] = 2.f * a[2] - p0.z; a[3] = 2.f * a[3] - p0.w;
        a[4] = 2.f * a[4] - p1.x; a[5] = 2.f * a[5] - p1.y;
        a[6] = 2.f * a[6] - p1.z; a[7] = 2.f * a[7] - p1.w;
    }
    xn[rb + lane * 2]     = make_float4(a[0], a[1], a[2], a[3]);
    xn[rb + lane * 2 + 1] = make_float4(a[4], a[5], a[6], a[7]);
    uint4 h;
    h.x = (unsigned)f2bf(a[0]) | ((unsigned)f2bf(a[1]) << 16);
    h.y = (unsigned)f2bf(a[2]) | ((unsigned)f2bf(a[3]) << 16);
    h.z = (unsigned)f2bf(a[4]) | ((unsigned)f2bf(a[5]) << 16);
    h.w = (unsigned)f2bf(a[6]) | ((unsigned)f2bf(a[7]) << 16);
    *(uint4*)&xnb[(size_t)m * Cn + lane * 8] = h;
}

// ---------------- W -> MFMA B-fragment pre-swizzle ----------------

__global__ __launch_bounds__(256) void k_wfrag(const float* __restrict__ W,
                                               ushort* __restrict__ wfrag) {
    int idx = blockIdx.x * 256 + threadIdx.x;   // 12*4*64*8 = 24576
    if (idx >= 12 * 4 * 64 * 8) return;
    int j    = idx & 7;
    int lane = (idx >> 3) & 63;
    int n    = (idx >> 9) & 3;
    int kk   = idx >> 11;
    int k    = (lane >> 4) * 8 + j;
    int lev  = kk >> 1;
    int f    = (kk & 1) * 32 + k;
    int fo   = n * 16 + (lane & 15);
    wfrag[idx] = f2bf(W[(f * Kn + lev) * FOUTn + fo]);
}

// ---------------- MFMA projection GEMM ----------------
// out[b, m, fo] (+)= sum over levels lev_base..lev_base+nlev-1, f:
//   Xlev[m, b*64+f] * W[(f*6+lev)*64+fo]
// Block: 256 thr (4 waves), tile 64 m x 64 fo, one b per block.

__global__ __launch_bounds__(256) void k_gemm_mfma(const ushort* __restrict__ xb,
                                                   const ushort* __restrict__ wfrag,
                                                   float* __restrict__ out,
                                                   int lev_base, int nlev,
                                                   int nslots, int accum) {
    __shared__ __align__(16) ushort As[64 * 40];   // 64 rows x 32 k, +8 pad
    int t    = threadIdx.x;
    int wv   = t >> 6;
    int lane = t & 63;
    int q    = lane >> 4, r = lane & 15;
    int b    = blockIdx.x & 7;
    int m0   = (blockIdx.x >> 3) * 64;

    floatx4 acc[4];
    acc[0] = (floatx4)0.f; acc[1] = (floatx4)0.f;
    acc[2] = (floatx4)0.f; acc[3] = (floatx4)0.f;

    int srow = t >> 2, spart = t & 3;   // staging: 64 rows x 4 x 16B
    int chunks = nlev * 2;
    for (int kk = 0; kk < chunks; ++kk) {
        int lev  = lev_base + (kk >> 1);
        int slot = lev % nslots;
        int f0   = (kk & 1) * 32;
        const ushort* src = xb + (size_t)slot * Mn * Cn
                          + (size_t)(m0 + srow) * Cn + b * 64 + f0 + spart * 8;
        uint4 v = *(const uint4*)src;
        __syncthreads();                       // prior chunk's LDS reads done
        *(uint4*)&As[srow * 40 + spart * 8] = v;
        __syncthreads();

        short8 af = *(const short8*)&As[(wv * 16 + r) * 40 + q * 8];
        int kkg = lev * 2 + (kk & 1);
        const ushort* wf = wfrag + ((size_t)(kkg * 4) * 64 + lane) * 8;
        acc[0] = __builtin_amdgcn_mfma_f32_16x16x32_bf16(af, *(const short8*)(wf),        acc[0], 0, 0, 0);
        acc[1] = __builtin_amdgcn_mfma_f32_16x16x32_bf16(af, *(const short8*)(wf + 512),  acc[1], 0, 0, 0);
        acc[2] = __builtin_amdgcn_mfma_f32_16x16x32_bf16(af, *(const short8*)(wf + 1024), acc[2], 0, 0, 0);
        acc[3] = __builtin_amdgcn_mfma_f32_16x16x32_bf16(af, *(const short8*)(wf + 1536), acc[3], 0, 0, 0);
    }

    // C/D layout: col = lane&15, row = (lane>>4)*4 + reg
    size_t obase = ((size_t)b * Mn + m0 + wv * 16) * FOUTn;
    for (int n = 0; n < 4; ++n) {
        for (int reg = 0; reg < 4; ++reg) {
            int row = q * 4 + reg;
            size_t o = obase + (size_t)row * FOUTn + n * 16 + r;
            float val = acc[n][reg];
            if (accum) val += out[o];
            out[o] = val;
        }
    }
}

// ---------------- fallback fp32 kernels (ws too small; not expected) ----------------

__global__ __launch_bounds__(256) void k_spmm_f32(const float4* __restrict__ xc,
                                                  const float4* __restrict__ xp,
                                                  float4* __restrict__ xn,
                                                  const int* __restrict__ rowptr,
                                                  const int2* __restrict__ csr,
                                                  int first) {
    int t = threadIdx.x;
    int lane = t & 63;
    int m = blockIdx.x * 4 + (t >> 6);
    size_t rb = (size_t)m * 128;
    float4 v0 = xc[rb + lane];
    float4 v1 = xc[rb + 64 + lane];
    float4 a0 = make_float4(-v0.x, -v0.y, -v0.z, -v0.w);
    float4 a1 = make_float4(-v1.x, -v1.y, -v1.z, -v1.w);
    int e = rowptr[m], end = rowptr[m + 1];
    for (; e < end; ++e) {
        int2 cv = csr[e];
        float w = __int_as_float(cv.y);
        const float4* r = xc + (size_t)cv.x * 128;
        float4 g0 = r[lane], g1 = r[64 + lane];
        a0.x += w * g0.x; a0.y += w * g0.y; a0.z += w * g0.z; a0.w += w * g0.w;
        a1.x += w * g1.x; a1.y += w * g1.y; a1.z += w * g1.z; a1.w += w * g1.w;
    }
    if (!first) {
        float4 p0 = xp[rb + lane];
        float4 p1 = xp[rb + 64 + lane];
        a0.x = 2.f * a0.x - p0.x; a0.y = 2.f * a0.y - p0.y;
        a0.z = 2.f * a0.z - p0.z; a0.w = 2.f * a0.w - p0.w;
        a1.x = 2.f * a1.x - p1.x; a1.y = 2.f * a1.y - p1.y;
        a1.z = 2.f * a1.z - p1.z; a1.w = 2.f * a1.w - p1.w;
    }
    xn[rb + lane] = a0;
    xn[rb + 64 + lane] = a1;
}

__global__ __launch_bounds__(256) void k_gemm2(const float* __restrict__ xa,
                                               const float* __restrict__ xb,
                                               const float* __restrict__ W,
                                               float* __restrict__ out,
                                               int ka, int kb, int accum) {
    __shared__ __align__(16) float Wa[64 * 64];
    __shared__ __align__(16) float Wb[64 * 64];
    __shared__ __align__(16) float xsa[4 * Cn];
    __shared__ __align__(16) float xsb[4 * Cn];
    int t = threadIdx.x;
    size_t m0 = (size_t)blockIdx.x * 4;
    for (int i = t; i < 4096; i += 256) {
        int f = i >> 6, fo = i & 63;
        Wa[i] = W[(f * Kn + ka) * FOUTn + fo];
        Wb[i] = W[(f * Kn + kb) * FOUTn + fo];
    }
    for (int i = t; i < 4 * Cn; i += 256) {
        xsa[i] = xa[m0 * Cn + i];
        xsb[i] = xb[m0 * Cn + i];
    }
    __syncthreads();
    int fo  = (t & 15) * 4;
    int idx = t >> 4;
    int m   = idx & 3;
    int bq  = idx >> 2;
    float4 acc0 = make_float4(0.f, 0.f, 0.f, 0.f);
    float4 acc1 = make_float4(0.f, 0.f, 0.f, 0.f);
    for (int f = 0; f < 64; ++f) {
        float4 wa = *(const float4*)&Wa[f * 64 + fo];
        float a0 = xsa[m * Cn + bq * 64 + f];
        float a1 = xsa[m * Cn + (bq + 4) * 64 + f];
        acc0.x += a0 * wa.x; acc0.y += a0 * wa.y; acc0.z += a0 * wa.z; acc0.w += a0 * wa.w;
        acc1.x += a1 * wa.x; acc1.y += a1 * wa.y; acc1.z += a1 * wa.z; acc1.w += a1 * wa.w;
        float4 wb = *(const float4*)&Wb[f * 64 + fo];
        float b0 = xsb[m * Cn + bq * 64 + f];
        float b1 = xsb[m * Cn + (bq + 4) * 64 + f];
        acc0.x += b0 * wb.x; acc0.y += b0 * wb.y; acc0.z += b0 * wb.z; acc0.w += b0 * wb.w;
        acc1.x += b1 * wb.x; acc1.y += b1 * wb.y; acc1.z += b1 * wb.z; acc1.w += b1 * wb.w;
    }
    size_t o0 = (((size_t)bq * Mn) + (m0 + m)) * FOUTn + fo;
    size_t o1 = (((size_t)(bq + 4) * Mn) + (m0 + m)) * FOUTn + fo;
    float4* out4_0 = (float4*)&out[o0];
    float4* out4_1 = (float4*)&out[o1];
    if (accum) {
        float4 c0 = *out4_0, c1 = *out4_1;
        acc0.x += c0.x; acc0.y += c0.y; acc0.z += c0.z; acc0.w += c0.w;
        acc1.x += c1.x; acc1.y += c1.y; acc1.z += c1.z; acc1.w += c1.w;
    }
    *out4_0 = acc0;
    *out4_1 = acc1;
}

// ---------------- launch ----------------

extern "C" void kernel_launch(void* const* d_in, const int* in_sizes, int n_in,
                              void* d_out, int out_size, void* d_ws, size_t ws_size,
                              hipStream_t stream) {
    const float* x         = (const float*)d_in[0];
    const float* edge_vals = (const float*)d_in[1];
    const float* W         = (const float*)d_in[2];
    const int*   edge_rows = (const int*)d_in[3];
    const int*   edge_cols = (const int*)d_in[4];
    float* out = (float*)d_out;

    char* ws = (char*)d_ws;
    const size_t bufB = (size_t)Mn * Cn * sizeof(float);   // 81.92 MB fp32 level
    const size_t bufH = (size_t)Mn * Cn * sizeof(ushort);  // 40.96 MB bf16 level
    const size_t wfB  = 12 * 4 * 64 * 8 * sizeof(ushort);  // 48 KB
    const size_t csrB = (size_t)(Mn + 4 + Mn) * 4 + (size_t)NNZn * 8;  // ~2.9 MB

    // plan: 2 fp32 recurrence buffers (in-place) + nslots bf16 levels
    int nslots;
    if      (ws_size >= 2 * bufB + 6 * bufH + wfB + csrB) nslots = 6;  // one GEMM
    else if (ws_size >= 2 * bufB + 3 * bufH + wfB + csrB) nslots = 3;  // two GEMMs
    else if (ws_size >= 2 * bufB + 2 * bufH + wfB + csrB) nslots = 2;  // three GEMMs
    else                                                  nslots = 0;  // fp32 fallback

    float*  buf0 = (float*)(ws);
    float*  buf1 = (float*)(ws + bufB);
    float*  buf2 = (float*)(ws + bufB);        // fallback-only third buffer alias fix below
    ushort* xbb  = (ushort*)(ws + 2 * bufB);
    ushort* wfr  = (ushort*)(ws + 2 * bufB + nslots * bufH);
    char*   csrbase = ws + 2 * bufB + nslots * bufH + (nslots ? wfB : 0);
    int*    rowptr  = (int*)csrbase;
    int*    fill    = rowptr + (Mn + 4);
    int2*   csr     = (int2*)(fill + Mn);

    // CSR build (every call; ws re-poisoned by harness)
    hipMemsetAsync(fill, 0, Mn * sizeof(int), stream);
    k_hist<<<(NNZn + 255) / 256, 256, 0, stream>>>(edge_rows, fill);
    k_scan<<<1, 1024, 0, stream>>>(fill, rowptr);
    hipMemsetAsync(fill, 0, Mn * sizeof(int), stream);
    k_scatter<<<(NNZn + 255) / 256, 256, 0, stream>>>(edge_rows, edge_cols, edge_vals,
                                                      rowptr, fill, csr);

    ushort* slotp[6];
    for (int l = 0; l < 6; ++l)
        slotp[l] = nslots ? (xbb + (size_t)(l % nslots) * Mn * Cn) : nullptr;

    const int spmm_grid = Mn / 4;
    const int gemm_grid = (Mn / 64) * 8;

    if (nslots >= 2) {
        k_wfrag<<<96, 256, 0, stream>>>(W, wfr);
        // x0 -> buf0 (+bf16 slot0); x1 -> buf1 (+bf16 slot1), gather from slot0
        k_transpose<<<Mn, 512, 0, stream>>>(x, buf0, slotp[0]);
        k_spmm_bf<<<spmm_grid, 256, 0, stream>>>((const float4*)buf0, (const float4*)buf0,
                                                 (float4*)buf1, slotp[1], slotp[0],
                                                 rowptr, csr, 1);
        if (nslots == 2)
            k_gemm_mfma<<<gemm_grid, 256, 0, stream>>>(xbb, wfr, out, 0, 2, nslots, 0);
        // x2 -> buf0 (in place over x0)
        k_spmm_bf<<<spmm_grid, 256, 0, stream>>>((const float4*)buf1, (const float4*)buf0,
                                                 (float4*)buf0, slotp[2], slotp[1],
                                                 rowptr, csr, 0);
        if (nslots == 3)
            k_gemm_mfma<<<gemm_grid, 256, 0, stream>>>(xbb, wfr, out, 0, 3, nslots, 0);
        // x3 -> buf1
        k_spmm_bf<<<spmm_grid, 256, 0, stream>>>((const float4*)buf0, (const float4*)buf1,
                                                 (float4*)buf1, slotp[3], slotp[2],
                                                 rowptr, csr, 0);
        if (nslots == 2)
            k_gemm_mfma<<<gemm_grid, 256, 0, stream>>>(xbb, wfr, out, 2, 2, nslots, 1);
        // x4 -> buf0 ; x5 -> buf1
        k_spmm_bf<<<spmm_grid, 256, 0, stream>>>((const float4*)buf1, (const float4*)buf0,
                                                 (float4*)buf0, slotp[4], slotp[3],
                                                 rowptr, csr, 0);
        k_spmm_bf<<<spmm_grid, 256, 0, stream>>>((const float4*)buf0, (const float4*)buf1,
                                                 (float4*)buf1, slotp[5], slotp[4],
                                                 rowptr, csr, 0);
        if (nslots == 6)
            k_gemm_mfma<<<gemm_grid, 256, 0, stream>>>(xbb, wfr, out, 0, 6, nslots, 0);
        else if (nslots == 3)
            k_gemm_mfma<<<gemm_grid, 256, 0, stream>>>(xbb, wfr, out, 3, 3, nslots, 1);
        else
            k_gemm_mfma<<<gemm_grid, 256, 0, stream>>>(xbb, wfr, out, 4, 2, nslots, 1);
    } else {
        // fp32 fallback: 3 rotating fp32 buffers (needs 3*bufB + csr)
        buf2 = (float*)(ws + 2 * bufB);
        rowptr  = (int*)(ws + 3 * bufB);
        fill    = rowptr + (Mn + 4);
        csr     = (int2*)(fill + Mn);
        hipMemsetAsync(fill, 0, Mn * sizeof(int), stream);
        k_hist<<<(NNZn + 255) / 256, 256, 0, stream>>>(edge_rows, fill);
        k_scan<<<1, 1024, 0, stream>>>(fill, rowptr);
        hipMemsetAsync(fill, 0, Mn * sizeof(int), stream);
        k_scatter<<<(NNZn + 255) / 256, 256, 0, stream>>>(edge_rows, edge_cols, edge_vals,
                                                          rowptr, fill, csr);
        k_transpose<<<Mn, 512, 0, stream>>>(x, buf0, nullptr);
        k_spmm_f32<<<spmm_grid, 256, 0, stream>>>((const float4*)buf0, (const float4*)buf0,
                                                  (float4*)buf1, rowptr, csr, 1);
        k_gemm2<<<Mn / 4, 256, 0, stream>>>(buf0, buf1, W, out, 0, 1, 0);
        k_spmm_f32<<<spmm_grid, 256, 0, stream>>>((const float4*)buf1, (const float4*)buf0,
                                                  (float4*)buf2, rowptr, csr, 0);
        k_spmm_f32<<<spmm_grid, 256, 0, stream>>>((const float4*)buf2, (const float4*)buf1,
                                                  (float4*)buf0, rowptr, csr, 0);
        k_gemm2<<<Mn / 4, 256, 0, stream>>>(buf2, buf0, W, out, 2, 3, 1);
        k_spmm_f32<<<spmm_grid, 256, 0, stream>>>((const float4*)buf0, (const float4*)buf2,
                                                  (float4*)buf1, rowptr, csr, 0);
        k_spmm_f32<<<spmm_grid, 256, 0, stream>>>((const float4*)buf1, (const float4*)buf0,
                                                  (float4*)buf2, rowptr, csr, 0);
        k_gemm2<<<Mn / 4, 256, 0, stream>>>(buf1, buf2, W, out, 4, 5, 1);
    }
}

// Round 5
// 669.378 us; speedup vs baseline: 1.9713x; 1.2195x over previous
//
#include <hip/hip_runtime.h>

// Problem constants (MeshConv: B=8, M=40000, FIN=64, K=6, FOUT=64, NNZ=320000)
#define Mn    40000
#define Bn    8
#define FINn  64
#define Kn    6
#define FOUTn 64
#define NNZn  320000
#define Cn    512   // FIN*B columns per Chebyshev level; layout c = b*64 + f

typedef _Float16 half8 __attribute__((ext_vector_type(8)));  // MFMA A/B frag
typedef __attribute__((ext_vector_type(4))) float floatx4;   // MFMA accumulator

__device__ __forceinline__ ushort f2h(float f) {
    _Float16 h = (_Float16)f;
    return *(ushort*)&h;
}

// ---------------- CSR build ----------------

__global__ __launch_bounds__(256) void k_hist(const int* __restrict__ rows,
                                              int* __restrict__ cnt) {
    int e = blockIdx.x * 256 + threadIdx.x;
    if (e < NNZn) atomicAdd(&cnt[rows[e]], 1);
}

// chunked scan: 1024 threads x 40 rows each; one 10-step LDS scan
__global__ __launch_bounds__(1024) void k_scan(const int* __restrict__ cnt,
                                               int* __restrict__ rowptr) {
    __shared__ int part[1024];
    int tid = threadIdx.x;
    int base = tid * 40;
    int s = 0;
    for (int i = 0; i < 40; ++i) {
        int r = base + i;
        if (r < Mn) s += cnt[r];
    }
    part[tid] = s;
    __syncthreads();
    for (int off = 1; off < 1024; off <<= 1) {
        int t = (tid >= off) ? part[tid - off] : 0;
        __syncthreads();
        part[tid] += t;
        __syncthreads();
    }
    int run = part[tid] - s;   // exclusive prefix of this chunk
    for (int i = 0; i < 40; ++i) {
        int r = base + i;
        if (r < Mn) { rowptr[r] = run; run += cnt[r]; }
    }
    if (tid == 1023) rowptr[Mn] = part[1023];
}

__global__ __launch_bounds__(256) void k_scatter(const int* __restrict__ rows,
                                                 const int* __restrict__ cols,
                                                 const float* __restrict__ vals,
                                                 const int* __restrict__ rowptr,
                                                 int* __restrict__ fill,
                                                 int2* __restrict__ csr) {
    int e = blockIdx.x * 256 + threadIdx.x;
    if (e < NNZn) {
        int r = rows[e];
        int p = rowptr[r] + atomicAdd(&fill[r], 1);
        int2 cv; cv.x = cols[e]; cv.y = __float_as_int(vals[e]);
        csr[p] = cv;
    }
}

// ---------------- x -> x0 (fp16): x0[m, b*64+f] = x[b,m,f] ----------------

__global__ __launch_bounds__(512) void k_transpose_h(const float* __restrict__ x,
                                                     ushort* __restrict__ x0h) {
    int m = blockIdx.x, t = threadIdx.x;       // t = b*64 + f
    int b = t >> 6, f = t & 63;
    float v = x[((size_t)b * Mn + m) * 64 + f];        // coalesced per wave
    x0h[(size_t)m * Cn + t] = f2h(v);                  // coalesced fp16 write
}

// ---------------- SpMM (all-fp16 state) + Chebyshev recurrence ----------------
// acc = -xc[m] + sum val * xc[col] (fp32 arithmetic, fp16 storage);
// xn = first ? acc : 2*acc - xp.  One row per wave: 64 lanes x 8 halves (16 B).

__device__ __forceinline__ void fmah8(float* a, uint4 g, float w) {
    union { uint4 u; _Float16 h[8]; } c; c.u = g;
#pragma unroll
    for (int i = 0; i < 8; ++i) a[i] += w * (float)c.h[i];
}

__global__ __launch_bounds__(256) void k_spmm_h(const ushort* __restrict__ xc,
                                                const ushort* __restrict__ xp,
                                                ushort* __restrict__ xn,
                                                const int* __restrict__ rowptr,
                                                const int2* __restrict__ csr,
                                                int first) {
    int t = threadIdx.x;
    int lane = t & 63;
    int m = blockIdx.x * 4 + (t >> 6);
    const uint4* xc4 = (const uint4*)xc;       // row = 64 uint4 (512 halves)
    uint4 v = xc4[(size_t)m * 64 + lane];
    float a[8];
    { union { uint4 u; _Float16 h[8]; } c; c.u = v;
#pragma unroll
      for (int i = 0; i < 8; ++i) a[i] = -(float)c.h[i]; }

    int e = rowptr[m], end = rowptr[m + 1];
    for (; e + 4 <= end; e += 4) {
        int2 cv0 = csr[e],     cv1 = csr[e + 1];
        int2 cv2 = csr[e + 2], cv3 = csr[e + 3];
        uint4 g0 = xc4[(size_t)cv0.x * 64 + lane];
        uint4 g1 = xc4[(size_t)cv1.x * 64 + lane];
        uint4 g2 = xc4[(size_t)cv2.x * 64 + lane];
        uint4 g3 = xc4[(size_t)cv3.x * 64 + lane];
        fmah8(a, g0, __int_as_float(cv0.y));
        fmah8(a, g1, __int_as_float(cv1.y));
        fmah8(a, g2, __int_as_float(cv2.y));
        fmah8(a, g3, __int_as_float(cv3.y));
    }
    for (; e < end; ++e) {
        int2 cv = csr[e];
        uint4 g = xc4[(size_t)cv.x * 64 + lane];
        fmah8(a, g, __int_as_float(cv.y));
    }

    if (!first) {
        uint4 p = ((const uint4*)xp)[(size_t)m * 64 + lane];
        union { uint4 u; _Float16 h[8]; } c; c.u = p;
#pragma unroll
        for (int i = 0; i < 8; ++i) a[i] = 2.f * a[i] - (float)c.h[i];
    }
    union { uint4 u; _Float16 h[8]; } s;
#pragma unroll
    for (int i = 0; i < 8; ++i) s.h[i] = (_Float16)a[i];
    ((uint4*)xn)[(size_t)m * 64 + lane] = s.u;
}

// ---------------- W -> MFMA B-fragment pre-swizzle (fp16) ----------------
// Wfrag[((kk*4 + n)*64 + lane)*8 + j] = f16( W[(f*6+lev)*64 + fo] )
//   kk = global K-chunk (0..11), lev = kk>>1, f = (kk&1)*32 + (lane>>4)*8 + j,
//   fo = n*16 + (lane&15)

__global__ __launch_bounds__(256) void k_wfrag(const float* __restrict__ W,
                                               ushort* __restrict__ wfrag) {
    int idx = blockIdx.x * 256 + threadIdx.x;   // 12*4*64*8 = 24576
    if (idx >= 12 * 4 * 64 * 8) return;
    int j    = idx & 7;
    int lane = (idx >> 3) & 63;
    int n    = (idx >> 9) & 3;
    int kk   = idx >> 11;
    int k    = (lane >> 4) * 8 + j;
    int lev  = kk >> 1;
    int f    = (kk & 1) * 32 + k;
    int fo   = n * 16 + (lane & 15);
    wfrag[idx] = f2h(W[(f * Kn + lev) * FOUTn + fo]);
}

// ---------------- MFMA projection GEMM (fp16 inputs, fp32 acc) ----------------
// out[b, m, fo] (+)= sum over levels lev_base..lev_base+nlev-1, f:
//   Xlev[m, b*64+f] * W[(f*6+lev)*64+fo]
// Block: 256 thr (4 waves), tile 64 m x 64 fo, one b per block. Slot = lev.

__global__ __launch_bounds__(256) void k_gemm_mfma(const ushort* __restrict__ xh,
                                                   const ushort* __restrict__ wfrag,
                                                   float* __restrict__ out,
                                                   int lev_base, int nlev, int accum) {
    __shared__ __align__(16) ushort As[64 * 40];   // 64 rows x 32 k, +8 pad
    int t    = threadIdx.x;
    int wv   = t >> 6;
    int lane = t & 63;
    int q    = lane >> 4, r = lane & 15;
    int b    = blockIdx.x & 7;
    int m0   = (blockIdx.x >> 3) * 64;

    floatx4 acc[4];
    acc[0] = (floatx4)0.f; acc[1] = (floatx4)0.f;
    acc[2] = (floatx4)0.f; acc[3] = (floatx4)0.f;

    int srow = t >> 2, spart = t & 3;   // staging: 64 rows x 4 x 16B
    int chunks = nlev * 2;
    for (int kk = 0; kk < chunks; ++kk) {
        int lev = lev_base + (kk >> 1);
        int f0  = (kk & 1) * 32;
        const ushort* src = xh + (size_t)lev * Mn * Cn
                          + (size_t)(m0 + srow) * Cn + b * 64 + f0 + spart * 8;
        uint4 v = *(const uint4*)src;
        __syncthreads();                       // prior chunk's LDS reads done
        *(uint4*)&As[srow * 40 + spart * 8] = v;
        __syncthreads();

        half8 af = *(const half8*)&As[(wv * 16 + r) * 40 + q * 8];
        int kkg = lev * 2 + (kk & 1);
        const ushort* wf = wfrag + ((size_t)(kkg * 4) * 64 + lane) * 8;
        acc[0] = __builtin_amdgcn_mfma_f32_16x16x32_f16(af, *(const half8*)(wf),        acc[0], 0, 0, 0);
        acc[1] = __builtin_amdgcn_mfma_f32_16x16x32_f16(af, *(const half8*)(wf + 512),  acc[1], 0, 0, 0);
        acc[2] = __builtin_amdgcn_mfma_f32_16x16x32_f16(af, *(const half8*)(wf + 1024), acc[2], 0, 0, 0);
        acc[3] = __builtin_amdgcn_mfma_f32_16x16x32_f16(af, *(const half8*)(wf + 1536), acc[3], 0, 0, 0);
    }

    // C/D layout: col = lane&15, row = (lane>>4)*4 + reg
    size_t obase = ((size_t)b * Mn + m0 + wv * 16) * FOUTn;
    for (int n = 0; n < 4; ++n) {
        for (int reg = 0; reg < 4; ++reg) {
            int row = q * 4 + reg;
            size_t o = obase + (size_t)row * FOUTn + n * 16 + r;
            float val = acc[n][reg];
            if (accum) val += out[o];
            out[o] = val;
        }
    }
}

// ---------------- fallback fp32 kernels (ws too small; not expected) ----------------

__global__ __launch_bounds__(512) void k_transpose_f(const float* __restrict__ x,
                                                     float* __restrict__ x0) {
    int m = blockIdx.x, t = threadIdx.x;
    int b = t >> 6, f = t & 63;
    x0[(size_t)m * Cn + t] = x[((size_t)b * Mn + m) * 64 + f];
}

__global__ __launch_bounds__(256) void k_spmm_f32(const float4* __restrict__ xc,
                                                  const float4* __restrict__ xp,
                                                  float4* __restrict__ xn,
                                                  const int* __restrict__ rowptr,
                                                  const int2* __restrict__ csr,
                                                  int first) {
    int t = threadIdx.x;
    int lane = t & 63;
    int m = blockIdx.x * 4 + (t >> 6);
    size_t rb = (size_t)m * 128;
    float4 v0 = xc[rb + lane];
    float4 v1 = xc[rb + 64 + lane];
    float4 a0 = make_float4(-v0.x, -v0.y, -v0.z, -v0.w);
    float4 a1 = make_float4(-v1.x, -v1.y, -v1.z, -v1.w);
    int e = rowptr[m], end = rowptr[m + 1];
    for (; e < end; ++e) {
        int2 cv = csr[e];
        float w = __int_as_float(cv.y);
        const float4* r = xc + (size_t)cv.x * 128;
        float4 g0 = r[lane], g1 = r[64 + lane];
        a0.x += w * g0.x; a0.y += w * g0.y; a0.z += w * g0.z; a0.w += w * g0.w;
        a1.x += w * g1.x; a1.y += w * g1.y; a1.z += w * g1.z; a1.w += w * g1.w;
    }
    if (!first) {
        float4 p0 = xp[rb + lane];
        float4 p1 = xp[rb + 64 + lane];
        a0.x = 2.f * a0.x - p0.x; a0.y = 2.f * a0.y - p0.y;
        a0.z = 2.f * a0.z - p0.z; a0.w = 2.f * a0.w - p0.w;
        a1.x = 2.f * a1.x - p1.x; a1.y = 2.f * a1.y - p1.y;
        a1.z = 2.f * a1.z - p1.z; a1.w = 2.f * a1.w - p1.w;
    }
    xn[rb + lane] = a0;
    xn[rb + 64 + lane] = a1;
}

__global__ __launch_bounds__(256) void k_gemm2(const float* __restrict__ xa,
                                               const float* __restrict__ xb,
                                               const float* __restrict__ W,
                                               float* __restrict__ out,
                                               int ka, int kb, int accum) {
    __shared__ __align__(16) float Wa[64 * 64];
    __shared__ __align__(16) float Wb[64 * 64];
    __shared__ __align__(16) float xsa[4 * Cn];
    __shared__ __align__(16) float xsb[4 * Cn];
    int t = threadIdx.x;
    size_t m0 = (size_t)blockIdx.x * 4;
    for (int i = t; i < 4096; i += 256) {
        int f = i >> 6, fo = i & 63;
        Wa[i] = W[(f * Kn + ka) * FOUTn + fo];
        Wb[i] = W[(f * Kn + kb) * FOUTn + fo];
    }
    for (int i = t; i < 4 * Cn; i += 256) {
        xsa[i] = xa[m0 * Cn + i];
        xsb[i] = xb[m0 * Cn + i];
    }
    __syncthreads();
    int fo  = (t & 15) * 4;
    int idx = t >> 4;
    int m   = idx & 3;
    int bq  = idx >> 2;
    float4 acc0 = make_float4(0.f, 0.f, 0.f, 0.f);
    float4 acc1 = make_float4(0.f, 0.f, 0.f, 0.f);
    for (int f = 0; f < 64; ++f) {
        float4 wa = *(const float4*)&Wa[f * 64 + fo];
        float a0 = xsa[m * Cn + bq * 64 + f];
        float a1 = xsa[m * Cn + (bq + 4) * 64 + f];
        acc0.x += a0 * wa.x; acc0.y += a0 * wa.y; acc0.z += a0 * wa.z; acc0.w += a0 * wa.w;
        acc1.x += a1 * wa.x; acc1.y += a1 * wa.y; acc1.z += a1 * wa.z; acc1.w += a1 * wa.w;
        float4 wb = *(const float4*)&Wb[f * 64 + fo];
        float b0 = xsb[m * Cn + bq * 64 + f];
        float b1 = xsb[m * Cn + (bq + 4) * 64 + f];
        acc0.x += b0 * wb.x; acc0.y += b0 * wb.y; acc0.z += b0 * wb.z; acc0.w += b0 * wb.w;
        acc1.x += b1 * wb.x; acc1.y += b1 * wb.y; acc1.z += b1 * wb.z; acc1.w += b1 * wb.w;
    }
    size_t o0 = (((size_t)bq * Mn) + (m0 + m)) * FOUTn + fo;
    size_t o1 = (((size_t)(bq + 4) * Mn) + (m0 + m)) * FOUTn + fo;
    float4* out4_0 = (float4*)&out[o0];
    float4* out4_1 = (float4*)&out[o1];
    if (accum) {
        float4 c0 = *out4_0, c1 = *out4_1;
        acc0.x += c0.x; acc0.y += c0.y; acc0.z += c0.z; acc0.w += c0.w;
        acc1.x += c1.x; acc1.y += c1.y; acc1.z += c1.z; acc1.w += c1.w;
    }
    *out4_0 = acc0;
    *out4_1 = acc1;
}

// ---------------- launch ----------------

extern "C" void kernel_launch(void* const* d_in, const int* in_sizes, int n_in,
                              void* d_out, int out_size, void* d_ws, size_t ws_size,
                              hipStream_t stream) {
    const float* x         = (const float*)d_in[0];
    const float* edge_vals = (const float*)d_in[1];
    const float* W         = (const float*)d_in[2];
    const int*   edge_rows = (const int*)d_in[3];
    const int*   edge_cols = (const int*)d_in[4];
    float* out = (float*)d_out;

    char* ws = (char*)d_ws;
    const size_t bufB = (size_t)Mn * Cn * sizeof(float);   // 81.92 MB fp32 level
    const size_t bufH = (size_t)Mn * Cn * sizeof(ushort);  // 40.96 MB fp16 level
    const size_t wfB  = 12 * 4 * 64 * 8 * sizeof(ushort);  // 48 KB
    const size_t csrB = (size_t)(Mn + 4 + Mn) * 4 + (size_t)NNZn * 8;  // ~2.9 MB

    const int spmm_grid = Mn / 4;
    const int gemm_grid = (Mn / 64) * 8;

    // primary plan: 6 fp16 level slots (248.69 MB total) — same requirement
    // as round-4's verified-fitting layout
    if (ws_size >= 6 * bufH + wfB + csrB) {
        ushort* xh  = (ushort*)ws;                       // slot l at xh + l*Mn*Cn
        ushort* wfr = (ushort*)(ws + 6 * bufH);
        int*    rowptr = (int*)(ws + 6 * bufH + wfB);
        int*    fill   = rowptr + (Mn + 4);
        int2*   csr    = (int2*)(fill + Mn);
        ushort* slot[6];
        for (int l = 0; l < 6; ++l) slot[l] = xh + (size_t)l * Mn * Cn;

        // CSR build (every call; ws re-poisoned by harness)
        hipMemsetAsync(fill, 0, Mn * sizeof(int), stream);
        k_hist<<<(NNZn + 255) / 256, 256, 0, stream>>>(edge_rows, fill);
        k_scan<<<1, 1024, 0, stream>>>(fill, rowptr);
        hipMemsetAsync(fill, 0, Mn * sizeof(int), stream);
        k_scatter<<<(NNZn + 255) / 256, 256, 0, stream>>>(edge_rows, edge_cols,
                                                          edge_vals, rowptr, fill, csr);
        k_wfrag<<<96, 256, 0, stream>>>(W, wfr);

        // x0, x1, x2 then GEMM over levels 0-2 while slots are LLC-hot
        k_transpose_h<<<Mn, 512, 0, stream>>>(x, slot[0]);
        k_spmm_h<<<spmm_grid, 256, 0, stream>>>(slot[0], slot[0], slot[1],
                                                rowptr, csr, 1);
        k_spmm_h<<<spmm_grid, 256, 0, stream>>>(slot[1], slot[0], slot[2],
                                                rowptr, csr, 0);
        k_gemm_mfma<<<gemm_grid, 256, 0, stream>>>(xh, wfr, out, 0, 3, 0);
        // x3, x4, x5 then GEMM over levels 3-5 (accumulate)
        k_spmm_h<<<spmm_grid, 256, 0, stream>>>(slot[2], slot[1], slot[3],
                                                rowptr, csr, 0);
        k_spmm_h<<<spmm_grid, 256, 0, stream>>>(slot[3], slot[2], slot[4],
                                                rowptr, csr, 0);
        k_spmm_h<<<spmm_grid, 256, 0, stream>>>(slot[4], slot[3], slot[5],
                                                rowptr, csr, 0);
        k_gemm_mfma<<<gemm_grid, 256, 0, stream>>>(xh, wfr, out, 3, 3, 1);
    } else {
        // fp32 fallback: 3 rotating fp32 buffers + fp32 vector GEMM
        float* buf0 = (float*)(ws);
        float* buf1 = (float*)(ws + bufB);
        float* buf2 = (float*)(ws + 2 * bufB);
        int*   rowptr = (int*)(ws + 3 * bufB);
        int*   fill   = rowptr + (Mn + 4);
        int2*  csr    = (int2*)(fill + Mn);
        hipMemsetAsync(fill, 0, Mn * sizeof(int), stream);
        k_hist<<<(NNZn + 255) / 256, 256, 0, stream>>>(edge_rows, fill);
        k_scan<<<1, 1024, 0, stream>>>(fill, rowptr);
        hipMemsetAsync(fill, 0, Mn * sizeof(int), stream);
        k_scatter<<<(NNZn + 255) / 256, 256, 0, stream>>>(edge_rows, edge_cols,
                                                          edge_vals, rowptr, fill, csr);
        k_transpose_f<<<Mn, 512, 0, stream>>>(x, buf0);
        k_spmm_f32<<<spmm_grid, 256, 0, stream>>>((const float4*)buf0, (const float4*)buf0,
                                                  (float4*)buf1, rowptr, csr, 1);
        k_gemm2<<<Mn / 4, 256, 0, stream>>>(buf0, buf1, W, out, 0, 1, 0);
        k_spmm_f32<<<spmm_grid, 256, 0, stream>>>((const float4*)buf1, (const float4*)buf0,
                                                  (float4*)buf2, rowptr, csr, 0);
        k_spmm_f32<<<spmm_grid, 256, 0, stream>>>((const float4*)buf2, (const float4*)buf1,
                                                  (float4*)buf0, rowptr, csr, 0);
        k_gemm2<<<Mn / 4, 256, 0, stream>>>(buf2, buf0, W, out, 2, 3, 1);
        k_spmm_f32<<<spmm_grid, 256, 0, stream>>>((const float4*)buf0, (const float4*)buf2,
                                                  (float4*)buf1, rowptr, csr, 0);
        k_spmm_f32<<<spmm_grid, 256, 0, stream>>>((const float4*)buf1, (const float4*)buf0,
                                                  (float4*)buf2, rowptr, csr, 0);
        k_gemm2<<<Mn / 4, 256, 0, stream>>>(buf1, buf2, W, out, 4, 5, 1);
    }
}